// Round 10
// baseline (206.010 us; speedup 1.0000x reference)
//
#include <hip/hip_runtime.h>
#include <math.h>

#define NN 50000
#define NE 640000
#define F  128
#define NB 196        // coarse buckets of 256 nodes
#define PACKB 12500   // NN/4 pack blocks
#define CHB 256       // chist blocks
#define ECHUNK 2500   // NE / CHB
#define WPAD 136      // 128 + 8 ushort pad
#define RPAD 16       // pad slots per row (>= unroll depth)
#define SRCW_N (NE + RPAD * NN)

typedef __attribute__((ext_vector_type(8))) short short8;
typedef __attribute__((ext_vector_type(4))) float floatx4;
typedef __attribute__((ext_vector_type(4))) unsigned uintx4;

__device__ inline unsigned f2bf_pk(float f0, float f1) {
    unsigned u0 = __float_as_uint(f0), u1 = __float_as_uint(f1);
    u0 = (u0 + 0x7fffu + ((u0 >> 16) & 1u)) >> 16;   // RNE
    u1 = (u1 + 0x7fffu + ((u1 >> 16) & 1u)) >> 16;
    return (u1 << 16) | u0;
}

__device__ inline unsigned ilv4(unsigned a, unsigned b) {
    a = (a | (a << 2)) & 0x33u; a = (a | (a << 1)) & 0x55u;
    b = (b | (b << 2)) & 0x33u; b = (b | (b << 1)) & 0x55u;
    return a | (b << 1);
}

// ---- fused: pack (blocks 0..PACKB) + coarse hist ----
__global__ __launch_bounds__(256) void pc_kernel(const float* __restrict__ x,
                                                 const float* __restrict__ mask,
                                                 const int* __restrict__ row,
                                                 const int* __restrict__ col,
                                                 unsigned* __restrict__ mx,
                                                 unsigned char* __restrict__ rec,
                                                 int* __restrict__ crow,
                                                 int* __restrict__ ccol) {
    if (blockIdx.x < PACKB) {
        int lane = threadIdx.x & 63;
        int n = blockIdx.x * 4 + (threadIdx.x >> 6);
        float2 xv = ((const float2*)x)[(size_t)n * 64 + lane];
        float2 mv = ((const float2*)mask)[(size_t)n * 64 + lane];
        float x0 = (xv.x != xv.x) ? 0.f : xv.x;
        float x1 = (xv.y != xv.y) ? 0.f : xv.y;
        float p0 = (mv.x != 0.f) ? x0 : 0.f;
        float p1 = (mv.y != 0.f) ? x1 : 0.f;
        mx[(size_t)n * 64 + lane] = f2bf_pk(p0, p1);
        unsigned long long b0 = __ballot(mv.x != 0.f);
        unsigned long long b1 = __ballot(mv.y != 0.f);
        if (lane < 16) {
            unsigned nib0 = (unsigned)(b0 >> (4 * lane)) & 0xFu;
            unsigned nib1 = (unsigned)(b1 >> (4 * lane)) & 0xFu;
            rec[(size_t)n * 16 + lane] = (unsigned char)ilv4(nib0, nib1);
        }
    } else {
        __shared__ int hr[NB], hc[NB];
        for (int i = threadIdx.x; i < NB; i += 256) { hr[i] = 0; hc[i] = 0; }
        __syncthreads();
        int bid = blockIdx.x - PACKB;
        int e0 = bid * ECHUNK, e1 = e0 + ECHUNK;
        for (int e = e0 + threadIdx.x; e < e1; e += 256) {
            atomicAdd(&hr[row[e] >> 8], 1);
            atomicAdd(&hc[col[e] >> 8], 1);
        }
        __syncthreads();
        for (int i = threadIdx.x; i < NB; i += 256) {
            atomicAdd(&crow[i], hr[i]);
            atomicAdd(&ccol[i], hc[i]);
        }
    }
}

// ---- scan coarse hists; rowstart_p[NN] = NE + RPAD*NN ----
__global__ __launch_bounds__(256) void cscan_kernel(const int* __restrict__ crow,
                                                    const int* __restrict__ ccol,
                                                    int* __restrict__ crow_base,
                                                    int* __restrict__ ccol_base,
                                                    int* __restrict__ crow_cur,
                                                    int* __restrict__ ccol_cur,
                                                    int* __restrict__ rowstart_p) {
    __shared__ int ws[4];
    int t = threadIdx.x, lane = t & 63, wid = t >> 6;
    {
        int v = (t < NB) ? crow[t] : 0;
        int incl = v;
        #pragma unroll
        for (int off = 1; off < 64; off <<= 1) { int s = __shfl_up(incl, off); if (lane >= off) incl += s; }
        if (lane == 63) ws[wid] = incl;
        __syncthreads();
        int wbase = 0;
        for (int k = 0; k < wid; k++) wbase += ws[k];
        int ex = wbase + incl - v;
        if (t < NB) { crow_base[t] = ex; crow_cur[t] = ex; }
        if (t == 0) { crow_base[NB] = NE; rowstart_p[NN] = NE + RPAD * NN; }
        __syncthreads();
    }
    {
        int v = (t < NB) ? ccol[t] : 0;
        int incl = v;
        #pragma unroll
        for (int off = 1; off < 64; off <<= 1) { int s = __shfl_up(incl, off); if (lane >= off) incl += s; }
        if (lane == 63) ws[wid] = incl;
        __syncthreads();
        int wbase = 0;
        for (int k = 0; k < wid; k++) wbase += ws[k];
        int ex = wbase + incl - v;
        if (t < NB) { ccol_base[t] = ex; ccol_cur[t] = ex; }
        if (t == 0) ccol_base[NB] = NE;
    }
}

// ---- bucket scatter ----
__global__ __launch_bounds__(256) void scatter_kernel(const int* __restrict__ row,
                                                      const int* __restrict__ col,
                                                      int* __restrict__ crow_cur,
                                                      int* __restrict__ ccol_cur,
                                                      unsigned* __restrict__ rrec,
                                                      unsigned char* __restrict__ crec) {
    __shared__ int cntR[NB], cntC[NB], curR[NB], curC[NB];
    for (int i = threadIdx.x; i < NB; i += 256) { cntR[i] = 0; cntC[i] = 0; }
    __syncthreads();
    int e0 = blockIdx.x * ECHUNK, e1 = e0 + ECHUNK;
    for (int e = e0 + threadIdx.x; e < e1; e += 256) {
        atomicAdd(&cntR[row[e] >> 8], 1);
        atomicAdd(&cntC[col[e] >> 8], 1);
    }
    __syncthreads();
    for (int i = threadIdx.x; i < NB; i += 256) {
        curR[i] = atomicAdd(&crow_cur[i], cntR[i]);
        curC[i] = atomicAdd(&ccol_cur[i], cntC[i]);
    }
    __syncthreads();
    for (int e = e0 + threadIdx.x; e < e1; e += 256) {
        int r = row[e], c = col[e];
        int pr = atomicAdd(&curR[r >> 8], 1);
        rrec[pr] = ((unsigned)(r & 255) << 16) | (unsigned)c;
        int pc = atomicAdd(&curC[c >> 8], 1);
        crec[pc] = (unsigned char)(c & 255);
    }
}

// ---- fine col hist -> dinv (runs BEFORE finerow) ----
__global__ __launch_bounds__(256) void finecol_kernel(const unsigned char* __restrict__ crec,
                                                      const int* __restrict__ ccol_base,
                                                      float* __restrict__ dinv) {
    __shared__ int hist[256];
    int b = blockIdx.x;
    int s0 = ccol_base[b], s1 = ccol_base[b + 1];
    int t = threadIdx.x;
    hist[t] = 0;
    __syncthreads();
    for (int j = s0 + t; j < s1; j += 256)
        atomicAdd(&hist[crec[j]], 1);
    __syncthreads();
    int node = b * 256 + t;
    if (node < NN) {
        int d = hist[t];
        dinv[node] = (d > 0) ? rsqrtf((float)d) : 0.0f;
    }
}

// ---- fine row sort -> padded CSR (RPAD zero slots/row) with embedded bf16 weights ----
__global__ __launch_bounds__(256) void finerow_kernel(const unsigned* __restrict__ rrec,
                                                      const int* __restrict__ crow_base,
                                                      const float* __restrict__ dinv,
                                                      int* __restrict__ rowstart_p,
                                                      unsigned* __restrict__ srcs_w) {
    __shared__ int hist[256];
    __shared__ int ws[4];
    int b = blockIdx.x;
    int s0 = crow_base[b], s1 = crow_base[b + 1];
    int t = threadIdx.x, lane = t & 63, wid = t >> 6;
    hist[t] = 0;
    __syncthreads();
    for (int j = s0 + t; j < s1; j += 256)
        atomicAdd(&hist[(rrec[j] >> 16) & 255], 1);
    __syncthreads();
    int v = hist[t];
    int incl = v;
    #pragma unroll
    for (int off = 1; off < 64; off <<= 1) { int s = __shfl_up(incl, off); if (lane >= off) incl += s; }
    if (lane == 63) ws[wid] = incl;
    __syncthreads();
    int wbase = 0;
    for (int k = 0; k < wid; k++) wbase += ws[k];
    int ex = wbase + incl - v;
    int pbase = s0 + (256 * RPAD) * b;     // padded bucket start
    int node = b * 256 + t;
    if (node < NN) rowstart_p[node] = pbase + ex + RPAD * t;
    hist[t] = ex + RPAD * t;               // padded in-bucket cursor
    __syncthreads();
    for (int j = s0 + t; j < s1; j += 256) {
        unsigned r2 = rrec[j];
        int c = r2 & 0xFFFF;
        int pos = atomicAdd(&hist[(r2 >> 16) & 255], 1);
        srcs_w[pbase + pos] = f2bf_pk(0.f, dinv[c]) | (unsigned)c;
    }
}

// ---- gather + fused ratio: one wave per dst node, 16 edges in flight ----
// lane = (sub, l16): lane-group sub owns edges {sub*4..sub*4+3} of each 16-pack
__global__ __launch_bounds__(256) void gather_kernel(
        const int* __restrict__ rowstart_p, const unsigned* __restrict__ srcs_w,
        const float* __restrict__ dinv,
        const uint4* __restrict__ mxv, const unsigned char* __restrict__ rec,
        unsigned* __restrict__ rb) {
    int lane = threadIdx.x & 63;
    int r = blockIdx.x * 4 + (threadIdx.x >> 6);
    int l16 = lane & 15, sub = lane >> 4;
    int s0p = rowstart_p[r];
    int L = rowstart_p[r + 1] - s0p - RPAD;   // true edge count
    float dr = dinv[r];
    floatx4 n0 = (floatx4)(0.f), n1 = (floatx4)(0.f);
    floatx4 d0 = (floatx4)(0.f), d1 = (floatx4)(0.f);
    float S = 0.f;

    for (int j = 0; j < L; j += 16) {
        uintx4 e4 = __builtin_nontemporal_load((const uintx4*)(srcs_w + s0p + j + sub * 4));
        #pragma unroll
        for (int g = 0; g < 4; g++) {
            unsigned u = e4[g];
            int c = u & 0xFFFFu;
            float w = __uint_as_float(u & 0xFFFF0000u);
            uint4 m4 = mxv[c * 16 + l16];
            unsigned mb = rec[c * 16 + l16];
            floatx4 fa, fb;
            fa.x = __uint_as_float(m4.x << 16); fa.y = __uint_as_float(m4.x & 0xffff0000u);
            fa.z = __uint_as_float(m4.y << 16); fa.w = __uint_as_float(m4.y & 0xffff0000u);
            fb.x = __uint_as_float(m4.z << 16); fb.y = __uint_as_float(m4.z & 0xffff0000u);
            fb.z = __uint_as_float(m4.w << 16); fb.w = __uint_as_float(m4.w & 0xffff0000u);
            n0 += w * fa;
            n1 += w * fb;
            d0.x += ((mb >> 0) & 1u) ? w : 0.f;
            d0.y += ((mb >> 1) & 1u) ? w : 0.f;
            d0.z += ((mb >> 2) & 1u) ? w : 0.f;
            d0.w += ((mb >> 3) & 1u) ? w : 0.f;
            d1.x += ((mb >> 4) & 1u) ? w : 0.f;
            d1.y += ((mb >> 5) & 1u) ? w : 0.f;
            d1.z += ((mb >> 6) & 1u) ? w : 0.f;
            d1.w += ((mb >> 7) & 1u) ? w : 0.f;
            S += w;
        }
    }

    float num[8] = {n0.x, n0.y, n0.z, n0.w, n1.x, n1.y, n1.z, n1.w};
    float den[8] = {d0.x, d0.y, d0.z, d0.w, d1.x, d1.y, d1.z, d1.w};
    #pragma unroll
    for (int q = 0; q < 8; q++) {
        num[q] += __shfl_xor(num[q], 16); num[q] += __shfl_xor(num[q], 32);
        den[q] += __shfl_xor(den[q], 16); den[q] += __shfl_xor(den[q], 32);
    }
    S += __shfl_xor(S, 16); S += __shfl_xor(S, 32);

    if (sub == 0) {
        float kf = dr * S;
        float o[8];
        #pragma unroll
        for (int q = 0; q < 8; q++)
            o[q] = (den[q] != 0.f) ? kf * num[q] * __builtin_amdgcn_rcpf(den[q]) : 0.f;
        uintx4 pk;
        pk[0] = f2bf_pk(o[0], o[1]);
        pk[1] = f2bf_pk(o[2], o[3]);
        pk[2] = f2bf_pk(o[4], o[5]);
        pk[3] = f2bf_pk(o[6], o[7]);
        __builtin_nontemporal_store(pk, (uintx4*)rb + (size_t)r * 16 + l16);
    }
}

// ---- out = Abf16 @ W^T + b via MFMA ----
__global__ __launch_bounds__(256) void gemm_kernel(const unsigned short* __restrict__ Ab,
                                                   const float* __restrict__ W,
                                                   const float* __restrict__ bias,
                                                   float* __restrict__ out) {
    __shared__ unsigned short Wlds[F * WPAD];
    int tid = threadIdx.x;

    for (int i = tid * 4; i < F * F; i += 256 * 4) {
        int c = i >> 7, k = i & 127;
        float4 v = *(const float4*)(W + i);
        unsigned lo = f2bf_pk(v.x, v.y);
        unsigned hi = f2bf_pk(v.z, v.w);
        *(uint2*)&Wlds[c * WPAD + k] = make_uint2(lo, hi);
    }
    __syncthreads();

    int lane = tid & 63, wid = tid >> 6;
    int m = lane & 15, quad = lane >> 4;
    int arow = blockIdx.x * 64 + wid * 16 + m;
    int lrow = (arow < NN) ? arow : (NN - 1);
    const unsigned short* Arow = Ab + (size_t)lrow * F + quad * 8;

    floatx4 acc[8];
    #pragma unroll
    for (int nt = 0; nt < 8; nt++) acc[nt] = (floatx4)(0.f);

    #pragma unroll
    for (int step = 0; step < 4; step++) {
        short8 af = *(const short8*)(Arow + step * 32);
        #pragma unroll
        for (int nt = 0; nt < 8; nt++) {
            short8 bf = *(const short8*)&Wlds[(nt * 16 + m) * WPAD + step * 32 + quad * 8];
            acc[nt] = __builtin_amdgcn_mfma_f32_16x16x32_bf16(af, bf, acc[nt], 0, 0, 0);
        }
    }

    int orow0 = blockIdx.x * 64 + wid * 16 + quad * 4;
    #pragma unroll
    for (int nt = 0; nt < 8; nt++) {
        float bv = bias[nt * 16 + m];
        #pragma unroll
        for (int p = 0; p < 4; p++) {
            int gr = orow0 + p;
            if (gr < NN)
                __builtin_nontemporal_store(acc[nt][p] + bv, out + (size_t)gr * F + nt * 16 + m);
        }
    }
}

extern "C" void kernel_launch(void* const* d_in, const int* in_sizes, int n_in,
                              void* d_out, int out_size, void* d_ws, size_t ws_size,
                              hipStream_t stream) {
    const float* x    = (const float*)d_in[0];
    const float* mask = (const float*)d_in[1];
    const int*   ei   = (const int*)d_in[2];
    const float* W    = (const float*)d_in[3];
    const float* b    = (const float*)d_in[4];
    float* out = (float*)d_out;

    const int* row = ei;
    const int* col = ei + NE;

    // ws layout
    unsigned*       mx        = (unsigned*)d_ws;                          // NN*64 u32
    unsigned*       rb        = mx + (size_t)NN * 64;                     // NN*64 u32
    unsigned*       srcs_w    = rb + (size_t)NN * 64;                     // SRCW_N u32
    unsigned*       rrec      = srcs_w + SRCW_N;                          // NE u32
    unsigned char*  rec       = (unsigned char*)(rrec + NE);              // NN*16 B
    unsigned char*  crec      = rec + (size_t)NN * 16;                    // NE u8
    float*          dinv      = (float*)(crec + NE);                      // NN f32
    int*            crow      = (int*)(dinv + NN);                        // NB
    int*            ccol      = crow + NB;                                // NB
    int*            crow_base = ccol + NB;                                // NB+1
    int*            ccol_base = crow_base + NB + 1;                       // NB+1
    int*            crow_cur  = ccol_base + NB + 1;                       // NB
    int*            ccol_cur  = crow_cur + NB;                            // NB
    int*            rowstart_p= ccol_cur + NB;                            // NN+1

    hipMemsetAsync(crow, 0, 2 * NB * sizeof(int), stream);
    hipMemsetAsync(srcs_w, 0, (size_t)SRCW_N * sizeof(unsigned), stream);

    pc_kernel<<<PACKB + CHB, 256, 0, stream>>>(x, mask, row, col, mx, rec, crow, ccol);
    cscan_kernel<<<1, 256, 0, stream>>>(crow, ccol, crow_base, ccol_base,
                                        crow_cur, ccol_cur, rowstart_p);
    scatter_kernel<<<CHB, 256, 0, stream>>>(row, col, crow_cur, ccol_cur, rrec, crec);
    finecol_kernel<<<NB, 256, 0, stream>>>(crec, ccol_base, dinv);
    finerow_kernel<<<NB, 256, 0, stream>>>(rrec, crow_base, dinv, rowstart_p, srcs_w);
    gather_kernel<<<NN / 4, 256, 0, stream>>>(rowstart_p, srcs_w, dinv,
                                              (const uint4*)mx, rec, rb);
    gemm_kernel<<<(NN + 63) / 64, 256, 0, stream>>>((const unsigned short*)rb, W, b, out);
}

// Round 11
// 202.750 us; speedup vs baseline: 1.0161x; 1.0161x over previous
//
#include <hip/hip_runtime.h>
#include <math.h>

#define NN 50000
#define NE 640000
#define F  128
#define NB 196        // coarse buckets of 256 nodes
#define PACKB 12500   // NN/4 pack blocks
#define CHB 256       // chist blocks
#define ECHUNK 2500   // NE / CHB
#define WPAD 136      // 128 + 8 ushort pad

typedef __attribute__((ext_vector_type(8))) short short8;
typedef __attribute__((ext_vector_type(4))) float floatx4;

__device__ inline unsigned f2bf_pk(float f0, float f1) {
    unsigned u0 = __float_as_uint(f0), u1 = __float_as_uint(f1);
    u0 = (u0 + 0x7fffu + ((u0 >> 16) & 1u)) >> 16;   // RNE
    u1 = (u1 + 0x7fffu + ((u1 >> 16) & 1u)) >> 16;
    return (u1 << 16) | u0;
}

__device__ inline unsigned ilv4(unsigned a, unsigned b) {
    a = (a | (a << 2)) & 0x33u; a = (a | (a << 1)) & 0x55u;
    b = (b | (b << 2)) & 0x33u; b = (b | (b << 1)) & 0x55u;
    return a | (b << 1);
}

// ---- fused: pack (blocks 0..PACKB) + coarse hist ----
// pack: mx[n] = 128 bf16 of mask*nan_to_num(x); rec[n][0..16) = mask bits
__global__ __launch_bounds__(256) void pc_kernel(const float* __restrict__ x,
                                                 const float* __restrict__ mask,
                                                 const int* __restrict__ row,
                                                 const int* __restrict__ col,
                                                 unsigned* __restrict__ mx,
                                                 unsigned char* __restrict__ rec,
                                                 int* __restrict__ crow,
                                                 int* __restrict__ ccol) {
    if (blockIdx.x < PACKB) {
        int lane = threadIdx.x & 63;
        int n = blockIdx.x * 4 + (threadIdx.x >> 6);
        float2 xv = ((const float2*)x)[(size_t)n * 64 + lane];
        float2 mv = ((const float2*)mask)[(size_t)n * 64 + lane];
        float x0 = (xv.x != xv.x) ? 0.f : xv.x;
        float x1 = (xv.y != xv.y) ? 0.f : xv.y;
        float p0 = (mv.x != 0.f) ? x0 : 0.f;
        float p1 = (mv.y != 0.f) ? x1 : 0.f;
        mx[(size_t)n * 64 + lane] = f2bf_pk(p0, p1);
        unsigned long long b0 = __ballot(mv.x != 0.f);
        unsigned long long b1 = __ballot(mv.y != 0.f);
        if (lane < 16) {
            unsigned nib0 = (unsigned)(b0 >> (4 * lane)) & 0xFu;
            unsigned nib1 = (unsigned)(b1 >> (4 * lane)) & 0xFu;
            rec[(size_t)n * 32 + lane] = (unsigned char)ilv4(nib0, nib1);
        }
    } else {
        __shared__ int hr[NB], hc[NB];
        for (int i = threadIdx.x; i < NB; i += 256) { hr[i] = 0; hc[i] = 0; }
        __syncthreads();
        int bid = blockIdx.x - PACKB;
        int e0 = bid * ECHUNK, e1 = e0 + ECHUNK;
        for (int e = e0 + threadIdx.x; e < e1; e += 256) {
            atomicAdd(&hr[row[e] >> 8], 1);
            atomicAdd(&hc[col[e] >> 8], 1);
        }
        __syncthreads();
        for (int i = threadIdx.x; i < NB; i += 256) {
            atomicAdd(&crow[i], hr[i]);
            atomicAdd(&ccol[i], hc[i]);
        }
    }
}

// ---- scan both coarse hists -> bases + cursors; rowstart[NN] = NE ----
__global__ __launch_bounds__(256) void cscan_kernel(const int* __restrict__ crow,
                                                    const int* __restrict__ ccol,
                                                    int* __restrict__ crow_base,
                                                    int* __restrict__ ccol_base,
                                                    int* __restrict__ crow_cur,
                                                    int* __restrict__ ccol_cur,
                                                    int* __restrict__ rowstart) {
    __shared__ int ws[4];
    int t = threadIdx.x, lane = t & 63, wid = t >> 6;
    {
        int v = (t < NB) ? crow[t] : 0;
        int incl = v;
        #pragma unroll
        for (int off = 1; off < 64; off <<= 1) { int s = __shfl_up(incl, off); if (lane >= off) incl += s; }
        if (lane == 63) ws[wid] = incl;
        __syncthreads();
        int wbase = 0;
        for (int k = 0; k < wid; k++) wbase += ws[k];
        int ex = wbase + incl - v;
        if (t < NB) { crow_base[t] = ex; crow_cur[t] = ex; }
        if (t == 0) { crow_base[NB] = NE; rowstart[NN] = NE; }
        __syncthreads();
    }
    {
        int v = (t < NB) ? ccol[t] : 0;
        int incl = v;
        #pragma unroll
        for (int off = 1; off < 64; off <<= 1) { int s = __shfl_up(incl, off); if (lane >= off) incl += s; }
        if (lane == 63) ws[wid] = incl;
        __syncthreads();
        int wbase = 0;
        for (int k = 0; k < wid; k++) wbase += ws[k];
        int ex = wbase + incl - v;
        if (t < NB) { ccol_base[t] = ex; ccol_cur[t] = ex; }
        if (t == 0) ccol_base[NB] = NE;
    }
}

// ---- bucket scatter: rrec = (row&255)<<16 | col keyed row>>8; crec = col&255 keyed col>>8 ----
__global__ __launch_bounds__(256) void scatter_kernel(const int* __restrict__ row,
                                                      const int* __restrict__ col,
                                                      int* __restrict__ crow_cur,
                                                      int* __restrict__ ccol_cur,
                                                      unsigned* __restrict__ rrec,
                                                      unsigned char* __restrict__ crec) {
    __shared__ int cntR[NB], cntC[NB], curR[NB], curC[NB];
    for (int i = threadIdx.x; i < NB; i += 256) { cntR[i] = 0; cntC[i] = 0; }
    __syncthreads();
    int e0 = blockIdx.x * ECHUNK, e1 = e0 + ECHUNK;
    for (int e = e0 + threadIdx.x; e < e1; e += 256) {
        atomicAdd(&cntR[row[e] >> 8], 1);
        atomicAdd(&cntC[col[e] >> 8], 1);
    }
    __syncthreads();
    for (int i = threadIdx.x; i < NB; i += 256) {
        curR[i] = atomicAdd(&crow_cur[i], cntR[i]);
        curC[i] = atomicAdd(&ccol_cur[i], cntC[i]);
    }
    __syncthreads();
    for (int e = e0 + threadIdx.x; e < e1; e += 256) {
        int r = row[e], c = col[e];
        int pr = atomicAdd(&curR[r >> 8], 1);
        rrec[pr] = ((unsigned)(r & 255) << 16) | (unsigned)c;
        int pc = atomicAdd(&curC[c >> 8], 1);
        crec[pc] = (unsigned char)(c & 255);
    }
}

// ---- fused fine pass: blocks 0..NB = row sort (rowstart+srcs); NB..2NB = col hist -> dinv into rec ----
__global__ __launch_bounds__(256) void fine_kernel(const unsigned* __restrict__ rrec,
                                                   const unsigned char* __restrict__ crec,
                                                   const int* __restrict__ crow_base,
                                                   const int* __restrict__ ccol_base,
                                                   int* __restrict__ rowstart,
                                                   unsigned short* __restrict__ srcs,
                                                   unsigned char* __restrict__ rec) {
    __shared__ int hist[256];
    __shared__ int ws[4];
    int t = threadIdx.x, lane = t & 63, wid = t >> 6;
    hist[t] = 0;
    __syncthreads();
    if (blockIdx.x < NB) {
        int b = blockIdx.x;
        int s0 = crow_base[b], s1 = crow_base[b + 1];
        for (int j = s0 + t; j < s1; j += 256)
            atomicAdd(&hist[(rrec[j] >> 16) & 255], 1);
        __syncthreads();
        int v = hist[t];
        int incl = v;
        #pragma unroll
        for (int off = 1; off < 64; off <<= 1) { int s = __shfl_up(incl, off); if (lane >= off) incl += s; }
        if (lane == 63) ws[wid] = incl;
        __syncthreads();
        int wbase = 0;
        for (int k = 0; k < wid; k++) wbase += ws[k];
        int ex = wbase + incl - v;
        int node = b * 256 + t;
        if (node < NN) rowstart[node] = s0 + ex;
        hist[t] = ex;
        __syncthreads();
        for (int j = s0 + t; j < s1; j += 256) {
            unsigned r2 = rrec[j];
            int pos = atomicAdd(&hist[(r2 >> 16) & 255], 1);
            srcs[s0 + pos] = (unsigned short)(r2 & 0xFFFFu);
        }
    } else {
        int b = blockIdx.x - NB;
        int s0 = ccol_base[b], s1 = ccol_base[b + 1];
        for (int j = s0 + t; j < s1; j += 256)
            atomicAdd(&hist[crec[j]], 1);
        __syncthreads();
        int node = b * 256 + t;
        if (node < NN) {
            int d = hist[t];
            float dv = (d > 0) ? rsqrtf((float)d) : 0.0f;
            *(float*)(rec + (size_t)node * 32 + 16) = dv;
        }
    }
}

// ---- gather + fused ratio: one wave per dst node, 8 edges in flight, bf16 out ----
__global__ __launch_bounds__(256) void gather_kernel(
        const int* __restrict__ rowstart, const unsigned short* __restrict__ srcs,
        const uint4* __restrict__ mxv, const unsigned char* __restrict__ rec,
        unsigned* __restrict__ rb) {
    int lane = threadIdx.x & 63;
    int r = blockIdx.x * 4 + (threadIdx.x >> 6);
    int l16 = lane & 15, sub = lane >> 4;
    int s0 = rowstart[r], s1 = rowstart[r + 1];
    float dr = *(const float*)(rec + (size_t)r * 32 + 16);
    float num[8] = {0.f,0.f,0.f,0.f,0.f,0.f,0.f,0.f};
    float den[8] = {0.f,0.f,0.f,0.f,0.f,0.f,0.f,0.f};
    float S = 0.f;

    for (int j = s0; j < s1; j += 8) {
        // group A: edges j+sub
        {
            int jj = j + sub;
            int cl = (jj < s1) ? jj : (s1 - 1);
            int c = __builtin_nontemporal_load(srcs + cl);
            float w = (jj < s1) ? *(const float*)(rec + (size_t)c * 32 + 16) : 0.f;
            uint4 u = mxv[(size_t)c * 16 + l16];
            unsigned mb = rec[(size_t)c * 32 + l16];
            float f[8];
            f[0] = __uint_as_float(u.x << 16); f[1] = __uint_as_float(u.x & 0xffff0000u);
            f[2] = __uint_as_float(u.y << 16); f[3] = __uint_as_float(u.y & 0xffff0000u);
            f[4] = __uint_as_float(u.z << 16); f[5] = __uint_as_float(u.z & 0xffff0000u);
            f[6] = __uint_as_float(u.w << 16); f[7] = __uint_as_float(u.w & 0xffff0000u);
            S += w;
            #pragma unroll
            for (int q = 0; q < 8; q++) {
                num[q] += w * f[q];
                den[q] += ((mb >> q) & 1u) ? w : 0.f;
            }
        }
        // group B: edges j+4+sub
        {
            int jj = j + 4 + sub;
            int cl = (jj < s1) ? jj : (s1 - 1);
            int c = __builtin_nontemporal_load(srcs + cl);
            float w = (jj < s1) ? *(const float*)(rec + (size_t)c * 32 + 16) : 0.f;
            uint4 u = mxv[(size_t)c * 16 + l16];
            unsigned mb = rec[(size_t)c * 32 + l16];
            float f[8];
            f[0] = __uint_as_float(u.x << 16); f[1] = __uint_as_float(u.x & 0xffff0000u);
            f[2] = __uint_as_float(u.y << 16); f[3] = __uint_as_float(u.y & 0xffff0000u);
            f[4] = __uint_as_float(u.z << 16); f[5] = __uint_as_float(u.z & 0xffff0000u);
            f[6] = __uint_as_float(u.w << 16); f[7] = __uint_as_float(u.w & 0xffff0000u);
            S += w;
            #pragma unroll
            for (int q = 0; q < 8; q++) {
                num[q] += w * f[q];
                den[q] += ((mb >> q) & 1u) ? w : 0.f;
            }
        }
    }

    #pragma unroll
    for (int q = 0; q < 8; q++) {
        num[q] += __shfl_xor(num[q], 16); num[q] += __shfl_xor(num[q], 32);
        den[q] += __shfl_xor(den[q], 16); den[q] += __shfl_xor(den[q], 32);
    }
    S += __shfl_xor(S, 16); S += __shfl_xor(S, 32);

    if (sub == 0) {
        float kf = dr * S;
        float o[8];
        #pragma unroll
        for (int q = 0; q < 8; q++)
            o[q] = (den[q] != 0.f) ? kf * num[q] / den[q] : 0.f;
        uint4 pk;
        pk.x = f2bf_pk(o[0], o[1]);
        pk.y = f2bf_pk(o[2], o[3]);
        pk.z = f2bf_pk(o[4], o[5]);
        pk.w = f2bf_pk(o[6], o[7]);
        ((uint4*)rb)[(size_t)r * 16 + l16] = pk;   // plain store: gemm re-reads rb via L2
    }
}

// ---- out = Abf16 @ W^T + b via MFMA (A read directly as bf16) ----
__global__ __launch_bounds__(256) void gemm_kernel(const unsigned short* __restrict__ Ab,
                                                   const float* __restrict__ W,
                                                   const float* __restrict__ bias,
                                                   float* __restrict__ out) {
    __shared__ unsigned short Wlds[F * WPAD];
    int tid = threadIdx.x;

    for (int i = tid * 4; i < F * F; i += 256 * 4) {
        int c = i >> 7, k = i & 127;
        float4 v = *(const float4*)(W + i);
        unsigned lo = f2bf_pk(v.x, v.y);
        unsigned hi = f2bf_pk(v.z, v.w);
        *(uint2*)&Wlds[c * WPAD + k] = make_uint2(lo, hi);
    }
    __syncthreads();

    int lane = tid & 63, wid = tid >> 6;
    int m = lane & 15, quad = lane >> 4;
    int arow = blockIdx.x * 64 + wid * 16 + m;
    int lrow = (arow < NN) ? arow : (NN - 1);
    const unsigned short* Arow = Ab + (size_t)lrow * F + quad * 8;

    floatx4 acc[8];
    #pragma unroll
    for (int nt = 0; nt < 8; nt++) acc[nt] = (floatx4)(0.f);

    #pragma unroll
    for (int step = 0; step < 4; step++) {
        short8 af = *(const short8*)(Arow + step * 32);
        #pragma unroll
        for (int nt = 0; nt < 8; nt++) {
            short8 bf = *(const short8*)&Wlds[(nt * 16 + m) * WPAD + step * 32 + quad * 8];
            acc[nt] = __builtin_amdgcn_mfma_f32_16x16x32_bf16(af, bf, acc[nt], 0, 0, 0);
        }
    }

    int orow0 = blockIdx.x * 64 + wid * 16 + quad * 4;
    #pragma unroll
    for (int nt = 0; nt < 8; nt++) {
        float bv = bias[nt * 16 + m];
        #pragma unroll
        for (int p = 0; p < 4; p++) {
            int gr = orow0 + p;
            if (gr < NN)
                __builtin_nontemporal_store(acc[nt][p] + bv, out + (size_t)gr * F + nt * 16 + m);
        }
    }
}

extern "C" void kernel_launch(void* const* d_in, const int* in_sizes, int n_in,
                              void* d_out, int out_size, void* d_ws, size_t ws_size,
                              hipStream_t stream) {
    const float* x    = (const float*)d_in[0];
    const float* mask = (const float*)d_in[1];
    const int*   ei   = (const int*)d_in[2];
    const float* W    = (const float*)d_in[3];
    const float* b    = (const float*)d_in[4];
    float* out = (float*)d_out;

    const int* row = ei;
    const int* col = ei + NE;

    // ws layout (16 B aligned segments first)
    unsigned*       mx        = (unsigned*)d_ws;                          // NN*64 u32 (12.8 MB)
    unsigned*       rb        = mx + (size_t)NN * 64;                     // NN*64 u32 bf16 ratio
    unsigned char*  rec       = (unsigned char*)(rb + (size_t)NN * 64);   // NN*32 B {bits16, dinv}
    unsigned*       rrec      = (unsigned*)(rec + (size_t)NN * 32);       // NE u32
    unsigned short* srcs      = (unsigned short*)(rrec + NE);             // NE u16
    unsigned char*  crec      = (unsigned char*)(srcs + NE);              // NE u8
    int*            crow      = (int*)(crec + NE);                        // NB
    int*            ccol      = crow + NB;                                // NB
    int*            crow_base = ccol + NB;                                // NB+1
    int*            ccol_base = crow_base + NB + 1;                       // NB+1
    int*            crow_cur  = ccol_base + NB + 1;                       // NB
    int*            ccol_cur  = crow_cur + NB;                            // NB
    int*            rowstart  = ccol_cur + NB;                            // NN+1

    hipMemsetAsync(crow, 0, 2 * NB * sizeof(int), stream);

    pc_kernel<<<PACKB + CHB, 256, 0, stream>>>(x, mask, row, col, mx, rec, crow, ccol);
    cscan_kernel<<<1, 256, 0, stream>>>(crow, ccol, crow_base, ccol_base,
                                        crow_cur, ccol_cur, rowstart);
    scatter_kernel<<<CHB, 256, 0, stream>>>(row, col, crow_cur, ccol_cur, rrec, crec);
    fine_kernel<<<2 * NB, 256, 0, stream>>>(rrec, crec, crow_base, ccol_base,
                                            rowstart, srcs, rec);
    gather_kernel<<<NN / 4, 256, 0, stream>>>(rowstart, srcs,
                                              (const uint4*)mx, rec, rb);
    gemm_kernel<<<(NN + 63) / 64, 256, 0, stream>>>((const unsigned short*)rb, W, b, out);
}

// Round 12
// 196.085 us; speedup vs baseline: 1.0506x; 1.0340x over previous
//
#include <hip/hip_runtime.h>
#include <math.h>

#define NN 50000
#define NE 640000
#define F  128
#define NB 196        // coarse buckets of 256 nodes
#define PACKB 12500   // NN/4 pack blocks
#define CHB 256       // chist blocks
#define ECHUNK 2500   // NE / CHB
#define WPAD 136      // 128 + 8 ushort pad
#define RPAD 8        // sentinel pad slots per row (>= gather unroll)
#define SRCS_N (NE + 256 * RPAD * NB)   // 1,041,408 u16

typedef __attribute__((ext_vector_type(8))) short short8;
typedef __attribute__((ext_vector_type(4))) float floatx4;

__device__ inline unsigned f2bf_pk(float f0, float f1) {
    unsigned u0 = __float_as_uint(f0), u1 = __float_as_uint(f1);
    u0 = (u0 + 0x7fffu + ((u0 >> 16) & 1u)) >> 16;   // RNE
    u1 = (u1 + 0x7fffu + ((u1 >> 16) & 1u)) >> 16;
    return (u1 << 16) | u0;
}

__device__ inline unsigned ilv4(unsigned a, unsigned b) {
    a = (a | (a << 2)) & 0x33u; a = (a | (a << 1)) & 0x55u;
    b = (b | (b << 2)) & 0x33u; b = (b | (b << 1)) & 0x55u;
    return a | (b << 1);
}

// ---- fused: pack (blocks 0..PACKB) + coarse hist ----
__global__ __launch_bounds__(256) void pc_kernel(const float* __restrict__ x,
                                                 const float* __restrict__ mask,
                                                 const int* __restrict__ row,
                                                 const int* __restrict__ col,
                                                 unsigned* __restrict__ mx,
                                                 unsigned char* __restrict__ rec,
                                                 int* __restrict__ crow,
                                                 int* __restrict__ ccol) {
    if (blockIdx.x < PACKB) {
        int lane = threadIdx.x & 63;
        int n = blockIdx.x * 4 + (threadIdx.x >> 6);
        float2 xv = ((const float2*)x)[(size_t)n * 64 + lane];
        float2 mv = ((const float2*)mask)[(size_t)n * 64 + lane];
        float x0 = (xv.x != xv.x) ? 0.f : xv.x;
        float x1 = (xv.y != xv.y) ? 0.f : xv.y;
        float p0 = (mv.x != 0.f) ? x0 : 0.f;
        float p1 = (mv.y != 0.f) ? x1 : 0.f;
        mx[(size_t)n * 64 + lane] = f2bf_pk(p0, p1);
        unsigned long long b0 = __ballot(mv.x != 0.f);
        unsigned long long b1 = __ballot(mv.y != 0.f);
        if (lane < 16) {
            unsigned nib0 = (unsigned)(b0 >> (4 * lane)) & 0xFu;
            unsigned nib1 = (unsigned)(b1 >> (4 * lane)) & 0xFu;
            rec[(size_t)n * 32 + lane] = (unsigned char)ilv4(nib0, nib1);
        }
    } else {
        __shared__ int hr[NB], hc[NB];
        for (int i = threadIdx.x; i < NB; i += 256) { hr[i] = 0; hc[i] = 0; }
        __syncthreads();
        int bid = blockIdx.x - PACKB;
        int e0 = bid * ECHUNK, e1 = e0 + ECHUNK;
        for (int e = e0 + threadIdx.x; e < e1; e += 256) {
            atomicAdd(&hr[row[e] >> 8], 1);
            atomicAdd(&hc[col[e] >> 8], 1);
        }
        __syncthreads();
        for (int i = threadIdx.x; i < NB; i += 256) {
            atomicAdd(&crow[i], hr[i]);
            atomicAdd(&ccol[i], hc[i]);
        }
    }
}

// ---- scan both coarse hists; also init sentinel node NN (mx row + rec = 0) ----
__global__ __launch_bounds__(256) void cscan_kernel(const int* __restrict__ crow,
                                                    const int* __restrict__ ccol,
                                                    int* __restrict__ crow_base,
                                                    int* __restrict__ ccol_base,
                                                    int* __restrict__ crow_cur,
                                                    int* __restrict__ ccol_cur,
                                                    int* __restrict__ rowstart_p,
                                                    unsigned* __restrict__ mx,
                                                    unsigned char* __restrict__ rec) {
    __shared__ int ws[4];
    int t = threadIdx.x, lane = t & 63, wid = t >> 6;
    if (t < 64) mx[(size_t)NN * 64 + t] = 0u;                 // sentinel mx row = 0
    if (t < 8)  ((unsigned*)(rec + (size_t)NN * 32))[t] = 0u; // sentinel bits+dinv = 0
    {
        int v = (t < NB) ? crow[t] : 0;
        int incl = v;
        #pragma unroll
        for (int off = 1; off < 64; off <<= 1) { int s = __shfl_up(incl, off); if (lane >= off) incl += s; }
        if (lane == 63) ws[wid] = incl;
        __syncthreads();
        int wbase = 0;
        for (int k = 0; k < wid; k++) wbase += ws[k];
        int ex = wbase + incl - v;
        if (t < NB) { crow_base[t] = ex; crow_cur[t] = ex; }
        if (t == 0) { crow_base[NB] = NE; rowstart_p[NN] = NE + RPAD * NN; }
        __syncthreads();
    }
    {
        int v = (t < NB) ? ccol[t] : 0;
        int incl = v;
        #pragma unroll
        for (int off = 1; off < 64; off <<= 1) { int s = __shfl_up(incl, off); if (lane >= off) incl += s; }
        if (lane == 63) ws[wid] = incl;
        __syncthreads();
        int wbase = 0;
        for (int k = 0; k < wid; k++) wbase += ws[k];
        int ex = wbase + incl - v;
        if (t < NB) { ccol_base[t] = ex; ccol_cur[t] = ex; }
        if (t == 0) ccol_base[NB] = NE;
    }
}

// ---- bucket scatter ----
__global__ __launch_bounds__(256) void scatter_kernel(const int* __restrict__ row,
                                                      const int* __restrict__ col,
                                                      int* __restrict__ crow_cur,
                                                      int* __restrict__ ccol_cur,
                                                      unsigned* __restrict__ rrec,
                                                      unsigned char* __restrict__ crec) {
    __shared__ int cntR[NB], cntC[NB], curR[NB], curC[NB];
    for (int i = threadIdx.x; i < NB; i += 256) { cntR[i] = 0; cntC[i] = 0; }
    __syncthreads();
    int e0 = blockIdx.x * ECHUNK, e1 = e0 + ECHUNK;
    for (int e = e0 + threadIdx.x; e < e1; e += 256) {
        atomicAdd(&cntR[row[e] >> 8], 1);
        atomicAdd(&cntC[col[e] >> 8], 1);
    }
    __syncthreads();
    for (int i = threadIdx.x; i < NB; i += 256) {
        curR[i] = atomicAdd(&crow_cur[i], cntR[i]);
        curC[i] = atomicAdd(&ccol_cur[i], cntC[i]);
    }
    __syncthreads();
    for (int e = e0 + threadIdx.x; e < e1; e += 256) {
        int r = row[e], c = col[e];
        int pr = atomicAdd(&curR[r >> 8], 1);
        rrec[pr] = ((unsigned)(r & 255) << 16) | (unsigned)c;
        int pc = atomicAdd(&curC[c >> 8], 1);
        crec[pc] = (unsigned char)(c & 255);
    }
}

// ---- fused fine pass: blocks 0..NB = row sort -> PADDED CSR (8 sentinel slots/node);
//      blocks NB..2NB = col hist -> dinv into rec ----
__global__ __launch_bounds__(256) void fine_kernel(const unsigned* __restrict__ rrec,
                                                   const unsigned char* __restrict__ crec,
                                                   const int* __restrict__ crow_base,
                                                   const int* __restrict__ ccol_base,
                                                   int* __restrict__ rowstart_p,
                                                   unsigned short* __restrict__ srcs,
                                                   unsigned char* __restrict__ rec) {
    __shared__ int hist[256];
    __shared__ int ws[4];
    int t = threadIdx.x, lane = t & 63, wid = t >> 6;
    hist[t] = 0;
    __syncthreads();
    if (blockIdx.x < NB) {
        int b = blockIdx.x;
        int s0 = crow_base[b], s1 = crow_base[b + 1];
        for (int j = s0 + t; j < s1; j += 256)
            atomicAdd(&hist[(rrec[j] >> 16) & 255], 1);
        __syncthreads();
        int v = hist[t];
        int incl = v;
        #pragma unroll
        for (int off = 1; off < 64; off <<= 1) { int s = __shfl_up(incl, off); if (lane >= off) incl += s; }
        if (lane == 63) ws[wid] = incl;
        __syncthreads();
        int wbase = 0;
        for (int k = 0; k < wid; k++) wbase += ws[k];
        int ex = wbase + incl - v;
        int pbase = s0 + (256 * RPAD) * b;          // padded bucket start
        int node = b * 256 + t;
        int nstart = pbase + ex + RPAD * t;
        if (node < NN) rowstart_p[node] = nstart;
        // write this node's RPAD sentinel pads (disjoint from data region)
        for (int k = 0; k < RPAD; k++)
            srcs[nstart + v + k] = (unsigned short)NN;
        hist[t] = ex + RPAD * t;                    // padded in-bucket cursor
        __syncthreads();
        for (int j = s0 + t; j < s1; j += 256) {
            unsigned r2 = rrec[j];
            int pos = atomicAdd(&hist[(r2 >> 16) & 255], 1);
            srcs[pbase + pos] = (unsigned short)(r2 & 0xFFFFu);
        }
    } else {
        int b = blockIdx.x - NB;
        int s0 = ccol_base[b], s1 = ccol_base[b + 1];
        for (int j = s0 + t; j < s1; j += 256)
            atomicAdd(&hist[crec[j]], 1);
        __syncthreads();
        int node = b * 256 + t;
        if (node < NN) {
            int d = hist[t];
            float dv = (d > 0) ? rsqrtf((float)d) : 0.0f;
            *(float*)(rec + (size_t)node * 32 + 16) = dv;
        }
    }
}

// ---- gather + fused ratio: clamp-free (sentinel pads), 8 edges in flight ----
__global__ __launch_bounds__(256) void gather_kernel(
        const int* __restrict__ rowstart_p, const unsigned short* __restrict__ srcs,
        const uint4* __restrict__ mxv, const unsigned char* __restrict__ rec,
        unsigned* __restrict__ rb) {
    int lane = threadIdx.x & 63;
    int r = blockIdx.x * 4 + (threadIdx.x >> 6);
    int l16 = lane & 15, sub = lane >> 4;
    int s0 = rowstart_p[r];
    int L = rowstart_p[r + 1] - s0 - RPAD;   // true edge count
    float dr = *(const float*)(rec + (size_t)r * 32 + 16);
    floatx4 n0 = (floatx4)(0.f), n1 = (floatx4)(0.f);
    floatx4 d0 = (floatx4)(0.f), d1 = (floatx4)(0.f);
    float S = 0.f;

    for (int j = 0; j < L; j += 8) {
        #pragma unroll
        for (int g = 0; g < 2; g++) {
            unsigned c = srcs[s0 + j + 4 * g + sub];
            unsigned roff = c * 32u;
            float w = *(const float*)(rec + roff + 16);
            unsigned mb = rec[roff + l16];
            uint4 u = mxv[c * 16u + l16];
            floatx4 fa, fb;
            fa.x = __uint_as_float(u.x << 16); fa.y = __uint_as_float(u.x & 0xffff0000u);
            fa.z = __uint_as_float(u.y << 16); fa.w = __uint_as_float(u.y & 0xffff0000u);
            fb.x = __uint_as_float(u.z << 16); fb.y = __uint_as_float(u.z & 0xffff0000u);
            fb.z = __uint_as_float(u.w << 16); fb.w = __uint_as_float(u.w & 0xffff0000u);
            n0 += w * fa;
            n1 += w * fb;
            d0.x += (mb & 1u) ? w : 0.f;
            d0.y += ((mb >> 1) & 1u) ? w : 0.f;
            d0.z += ((mb >> 2) & 1u) ? w : 0.f;
            d0.w += ((mb >> 3) & 1u) ? w : 0.f;
            d1.x += ((mb >> 4) & 1u) ? w : 0.f;
            d1.y += ((mb >> 5) & 1u) ? w : 0.f;
            d1.z += ((mb >> 6) & 1u) ? w : 0.f;
            d1.w += ((mb >> 7) & 1u) ? w : 0.f;
            S += w;
        }
    }

    float num[8] = {n0.x, n0.y, n0.z, n0.w, n1.x, n1.y, n1.z, n1.w};
    float den[8] = {d0.x, d0.y, d0.z, d0.w, d1.x, d1.y, d1.z, d1.w};
    #pragma unroll
    for (int q = 0; q < 8; q++) {
        num[q] += __shfl_xor(num[q], 16); num[q] += __shfl_xor(num[q], 32);
        den[q] += __shfl_xor(den[q], 16); den[q] += __shfl_xor(den[q], 32);
    }
    S += __shfl_xor(S, 16); S += __shfl_xor(S, 32);

    if (sub == 0) {
        float kf = dr * S;
        float o[8];
        #pragma unroll
        for (int q = 0; q < 8; q++)
            o[q] = (den[q] != 0.f) ? kf * num[q] / den[q] : 0.f;
        uint4 pk;
        pk.x = f2bf_pk(o[0], o[1]);
        pk.y = f2bf_pk(o[2], o[3]);
        pk.z = f2bf_pk(o[4], o[5]);
        pk.w = f2bf_pk(o[6], o[7]);
        ((uint4*)rb)[(size_t)r * 16 + l16] = pk;   // plain store: gemm re-reads via L2
    }
}

// ---- out = Abf16 @ W^T + b via MFMA ----
__global__ __launch_bounds__(256) void gemm_kernel(const unsigned short* __restrict__ Ab,
                                                   const float* __restrict__ W,
                                                   const float* __restrict__ bias,
                                                   float* __restrict__ out) {
    __shared__ unsigned short Wlds[F * WPAD];
    int tid = threadIdx.x;

    for (int i = tid * 4; i < F * F; i += 256 * 4) {
        int c = i >> 7, k = i & 127;
        float4 v = *(const float4*)(W + i);
        unsigned lo = f2bf_pk(v.x, v.y);
        unsigned hi = f2bf_pk(v.z, v.w);
        *(uint2*)&Wlds[c * WPAD + k] = make_uint2(lo, hi);
    }
    __syncthreads();

    int lane = tid & 63, wid = tid >> 6;
    int m = lane & 15, quad = lane >> 4;
    int arow = blockIdx.x * 64 + wid * 16 + m;
    int lrow = (arow < NN) ? arow : (NN - 1);
    const unsigned short* Arow = Ab + (size_t)lrow * F + quad * 8;

    floatx4 acc[8];
    #pragma unroll
    for (int nt = 0; nt < 8; nt++) acc[nt] = (floatx4)(0.f);

    #pragma unroll
    for (int step = 0; step < 4; step++) {
        short8 af = *(const short8*)(Arow + step * 32);
        #pragma unroll
        for (int nt = 0; nt < 8; nt++) {
            short8 bf = *(const short8*)&Wlds[(nt * 16 + m) * WPAD + step * 32 + quad * 8];
            acc[nt] = __builtin_amdgcn_mfma_f32_16x16x32_bf16(af, bf, acc[nt], 0, 0, 0);
        }
    }

    int orow0 = blockIdx.x * 64 + wid * 16 + quad * 4;
    #pragma unroll
    for (int nt = 0; nt < 8; nt++) {
        float bv = bias[nt * 16 + m];
        #pragma unroll
        for (int p = 0; p < 4; p++) {
            int gr = orow0 + p;
            if (gr < NN)
                __builtin_nontemporal_store(acc[nt][p] + bv, out + (size_t)gr * F + nt * 16 + m);
        }
    }
}

extern "C" void kernel_launch(void* const* d_in, const int* in_sizes, int n_in,
                              void* d_out, int out_size, void* d_ws, size_t ws_size,
                              hipStream_t stream) {
    const float* x    = (const float*)d_in[0];
    const float* mask = (const float*)d_in[1];
    const int*   ei   = (const int*)d_in[2];
    const float* W    = (const float*)d_in[3];
    const float* b    = (const float*)d_in[4];
    float* out = (float*)d_out;

    const int* row = ei;
    const int* col = ei + NE;

    // ws layout (sentinel node NN: mx has NN+1 rows, rec has NN+1 records)
    unsigned*       mx        = (unsigned*)d_ws;                            // (NN+1)*64 u32
    unsigned*       rb        = mx + (size_t)(NN + 1) * 64;                 // NN*64 u32
    unsigned char*  rec       = (unsigned char*)(rb + (size_t)NN * 64);     // (NN+1)*32 B
    unsigned*       rrec      = (unsigned*)(rec + (size_t)(NN + 1) * 32);   // NE u32
    unsigned short* srcs      = (unsigned short*)(rrec + NE);               // SRCS_N u16
    unsigned char*  crec      = (unsigned char*)(srcs + SRCS_N);            // NE u8
    int*            crow      = (int*)(crec + NE);                          // NB
    int*            ccol      = crow + NB;                                  // NB
    int*            crow_base = ccol + NB;                                  // NB+1
    int*            ccol_base = crow_base + NB + 1;                         // NB+1
    int*            crow_cur  = ccol_base + NB + 1;                         // NB
    int*            ccol_cur  = crow_cur + NB;                              // NB
    int*            rowstart_p= ccol_cur + NB;                              // NN+1

    hipMemsetAsync(crow, 0, 2 * NB * sizeof(int), stream);

    pc_kernel<<<PACKB + CHB, 256, 0, stream>>>(x, mask, row, col, mx, rec, crow, ccol);
    cscan_kernel<<<1, 256, 0, stream>>>(crow, ccol, crow_base, ccol_base,
                                        crow_cur, ccol_cur, rowstart_p, mx, rec);
    scatter_kernel<<<CHB, 256, 0, stream>>>(row, col, crow_cur, ccol_cur, rrec, crec);
    fine_kernel<<<2 * NB, 256, 0, stream>>>(rrec, crec, crow_base, ccol_base,
                                            rowstart_p, srcs, rec);
    gather_kernel<<<NN / 4, 256, 0, stream>>>(rowstart_p, srcs,
                                              (const uint4*)mx, rec, rb);
    gemm_kernel<<<(NN + 63) / 64, 256, 0, stream>>>((const unsigned short*)rb, W, b, out);
}